// Round 1
// baseline (265.700 us; speedup 1.0000x reference)
//
#include <hip/hip_runtime.h>
#include <hip/hip_bf16.h>

// out[w] = -sum_{n,h} log( x[n, q(n,h,w), h, w] )
// q = clamp(floor((y[n,0,h,w]+110)/10),0,20)*21 + clamp(floor((y[n,1,h,w]+110)/10),0,20)
//
// Shapes: x [8,441,128,128] f32, y [8,2,128,128] f32, out [128] f32.
// One block per w (128 blocks), 256 threads sweep the 1024 (n,h) pairs.
// Deterministic block reduction; no atomics, no workspace.

#define N_ 8
#define H_ 128
#define W_ 128
#define Q_ 441

__global__ __launch_bounds__(256) void MultinomialCELoss_kernel(
    const float* __restrict__ x, const float* __restrict__ y,
    float* __restrict__ out) {
    const int w = blockIdx.x;   // 0..127
    const int t = threadIdx.x;  // 0..255

    float acc = 0.0f;

    // 1024 (n,h) pairs, 4 per thread
    for (int e = t; e < N_ * H_; e += 256) {
        const int n = e >> 7;       // / 128
        const int h = e & 127;      // % 128

        // y[n, c, h, w]: offset ((n*2 + c)*128 + h)*128 + w
        const int ybase = ((n * 2) * H_ + h) * W_ + w;
        const float ya = y[ybase];
        const float yb = y[ybase + H_ * W_];

        // match reference exactly: floor((y - (-110))/10), clamp [0,20]
        int qa = (int)floorf((ya + 110.0f) / 10.0f);
        int qb = (int)floorf((yb + 110.0f) / 10.0f);
        qa = min(max(qa, 0), 20);
        qb = min(max(qb, 0), 20);
        const int q = qa * 21 + qb;

        // x[n, q, h, w]
        const size_t xoff = (((size_t)n * Q_ + q) * H_ + h) * W_ + w;
        acc += logf(x[xoff]);
    }

    // wave-64 shuffle reduction
    #pragma unroll
    for (int off = 32; off > 0; off >>= 1)
        acc += __shfl_down(acc, off, 64);

    // cross-wave reduction (4 waves)
    __shared__ float smem[4];
    const int wave = t >> 6;
    const int lane = t & 63;
    if (lane == 0) smem[wave] = acc;
    __syncthreads();

    if (t == 0) {
        float total = smem[0] + smem[1] + smem[2] + smem[3];
        out[w] = -total;
    }
}

extern "C" void kernel_launch(void* const* d_in, const int* in_sizes, int n_in,
                              void* d_out, int out_size, void* d_ws, size_t ws_size,
                              hipStream_t stream) {
    const float* x = (const float*)d_in[0];
    const float* y = (const float*)d_in[1];
    float* out = (float*)d_out;
    MultinomialCELoss_kernel<<<W_, 256, 0, stream>>>(x, y, out);
}

// Round 2
// 264.133 us; speedup vs baseline: 1.0059x; 1.0059x over previous
//
#include <hip/hip_runtime.h>
#include <hip/hip_bf16.h>

// out[w] = -sum_{n,h} log( x[n, q(n,h,w), h, w] )
// q = clamp(floor((y[n,0,h,w]+110)/10),0,20)*21 + clamp(floor((y[n,1,h,w]+110)/10),0,20)
//
// Shapes: x [8,441,128,128] f32, y [8,2,128,128] f32, out [128] f32.
//
// Two-pass deterministic reduction:
//   Kernel A: 1024 blocks (one per (n,h) row) x 128 threads (lane = w).
//             y loads coalesced; x gather scattered (inherent); partial
//             per-(row,w) log values written coalesced to d_ws [1024 x 128].
//   Kernel B: 128 blocks (one per w) x 256 threads; sums the 1024 partials
//             for its w (L2-resident, 512 KB total), writes out[w] = -total.

#define N_ 8
#define H_ 128
#define W_ 128
#define Q_ 441
#define NROWS (N_ * H_)   // 1024

__global__ __launch_bounds__(128) void mce_partial_kernel(
    const float* __restrict__ x, const float* __restrict__ y,
    float* __restrict__ ws) {
    const int row = blockIdx.x;     // 0..1023 == n*128 + h
    const int w   = threadIdx.x;    // 0..127  (lane dim -> coalesced)
    const int n = row >> 7;
    const int h = row & 127;

    // y[n, c, h, w]: contiguous in w -> coalesced 512B row reads
    const int ybase = ((n * 2) * H_ + h) * W_ + w;
    const float ya = y[ybase];
    const float yb = y[ybase + H_ * W_];

    // match reference exactly: floor((y + 110)/10), clamp [0,20]
    int qa = (int)floorf((ya + 110.0f) / 10.0f);
    int qb = (int)floorf((yb + 110.0f) / 10.0f);
    qa = min(max(qa, 0), 20);
    qb = min(max(qb, 0), 20);
    const int q = qa * 21 + qb;

    // x[n, q, h, w] — scattered gather (q random per lane)
    const size_t xoff = (((size_t)n * Q_ + q) * H_ + h) * W_ + w;
    ws[row * W_ + w] = logf(x[xoff]);
}

__global__ __launch_bounds__(256) void mce_reduce_kernel(
    const float* __restrict__ ws, float* __restrict__ out) {
    const int w = blockIdx.x;   // 0..127
    const int t = threadIdx.x;  // 0..255

    // each thread sums 4 of the 1024 row-partials for this w
    float acc = 0.0f;
    #pragma unroll
    for (int k = 0; k < NROWS / 256; ++k)
        acc += ws[(t + k * 256) * W_ + w];

    // wave-64 shuffle reduction
    #pragma unroll
    for (int off = 32; off > 0; off >>= 1)
        acc += __shfl_down(acc, off, 64);

    __shared__ float smem[4];
    const int wave = t >> 6;
    const int lane = t & 63;
    if (lane == 0) smem[wave] = acc;
    __syncthreads();

    if (t == 0)
        out[w] = -(smem[0] + smem[1] + smem[2] + smem[3]);
}

extern "C" void kernel_launch(void* const* d_in, const int* in_sizes, int n_in,
                              void* d_out, int out_size, void* d_ws, size_t ws_size,
                              hipStream_t stream) {
    const float* x = (const float*)d_in[0];
    const float* y = (const float*)d_in[1];
    float* out = (float*)d_out;
    float* ws  = (float*)d_ws;   // needs 1024*128*4 = 512 KB

    mce_partial_kernel<<<NROWS, 128, 0, stream>>>(x, y, ws);
    mce_reduce_kernel<<<W_, 256, 0, stream>>>(ws, out);
}